// Round 10
// baseline (1392.038 us; speedup 1.0000x reference)
//
#include <hip/hip_runtime.h>

typedef unsigned short u16;
using f16x8 = __attribute__((ext_vector_type(8))) _Float16;  // 8 fp16 (4 VGPRs)
using f32x4 = __attribute__((ext_vector_type(4))) float;

#define V_N 16384
#define M_N 32768

__device__ __forceinline__ float h2f(u16 u) {
  _Float16 h; __builtin_memcpy(&h, &u, 2); return (float)h;
}
__device__ __forceinline__ u16 f2h(float f) {
  _Float16 h = (_Float16)f; u16 u; __builtin_memcpy(&u, &h, 2); return u;
}

// async global->LDS DMA, 16B per lane; LDS dest = wave-uniform base + lane*16
__device__ __forceinline__ void dma16(const u16* g, u16* l) {
  __builtin_amdgcn_global_load_lds(
      (const __attribute__((address_space(1))) void*)(const void*)g,
      (__attribute__((address_space(3))) void*)(void*)l, 16, 0, 0);
}

// ---------- prep kernels ----------
// Weight permute to FRAGMENT-MAJOR: dst[kc][col][lq][j] (kc = k>>5, lq=(k>>3)&3,
// j=k&7, k = tap*256 + c). One B-load instr = contiguous 1KB (R5/R6 lesson).
__global__ __launch_bounds__(256) void perm2_k(const float* __restrict__ w, u16* __restrict__ wp) {
  int o = blockIdx.x & 255, layer = blockIdx.x >> 8;
  int t = threadIdx.x;                       // t = input channel c
  const float* src = w + ((size_t)layer * 256 + o) * 3072;
  u16* dst = wp + (size_t)layer * 786432;    // frag-major layer base
  float2 v[6];
  #pragma unroll
  for (int q = 0; q < 6; ++q) v[q] = *(const float2*)(src + t * 12 + q * 2);
  const float* vf = (const float*)v;         // vf[m] = w[o][c=t, tap=m]
  int lo = t & 31;                           // (k&31) = lq*8+j
  #pragma unroll
  for (int m = 0; m < 12; ++m) {
    int kc = m * 8 + (t >> 5);               // k = m*256 + t
    dst[(size_t)kc * 8192 + o * 32 + lo] = f2h(vf[m]);
  }
}

// generic f32 [O][K] row-major -> frag-major fp16 [kc][256][lq][j], zero-pad col>=O
__global__ __launch_bounds__(256) void permfr_k(const float* __restrict__ src, u16* __restrict__ dst,
                                                int O, int K) {
  int i = blockIdx.x * 256 + threadIdx.x;
  if (i >= (K << 8)) return;
  int j = i & 7, lq = (i >> 3) & 3, col = (i >> 5) & 255, kc = i >> 13;
  int k = kc * 32 + lq * 8 + j;
  float v = (col < O) ? src[(size_t)col * K + k] : 0.f;
  dst[i] = f2h(v);
}

// per-batch SE-scale fold into frag-major weights
__global__ __launch_bounds__(256) void wscale_k(const u16* __restrict__ w, const float* __restrict__ sig,
                                                const float* __restrict__ sigx,
                                                u16* __restrict__ o, int n, int sel) {
  int i = blockIdx.x * 256 + threadIdx.x;
  if (i >= n) return;
  float wv = h2f(w[i]);
  int k = (i >> 13) * 32 + ((i >> 3) & 3) * 8 + (i & 7);
  int c = k & 255;
  #pragma unroll
  for (int b = 0; b < 2; ++b) {
    float s;
    if (sel == 511 && k < 256) s = sigx ? sigx[b * 256 + c] : 1.f;
    else                       s = sig[b * 256 + c];
    o[(long)b * n + i] = f2h(wv * s);
  }
}

// ---------- encoder block 0 conv (C_in=3, K=36) + FUSED channel stats ----------
__global__ __launch_bounds__(256) void enc0_k(const float* __restrict__ verts, const int* __restrict__ sp,
                                              const float* __restrict__ w0, u16* __restrict__ y,
                                              float* __restrict__ st) {
  __shared__ float xs[32][36];
  int t = threadIdx.x;
  int r0 = blockIdx.x * 32;
  for (int s = t; s < 32 * 12; s += 256) {
    int row = s / 12, tt = s - row * 12;
    int gr = r0 + row;
    int b = gr >> 14, v = gr & (V_N - 1);
    int j = sp[tt * V_N + v];
    const float* p = verts + ((long)b * V_N + j) * 3;
    xs[row][tt]      = p[0];
    xs[row][12 + tt] = p[1];
    xs[row][24 + tt] = p[2];
  }
  __syncthreads();
  float w[36];
  #pragma unroll
  for (int k = 0; k < 36; ++k) w[k] = w0[t * 36 + k];
  float s1 = 0.f, s2 = 0.f;
  for (int row = 0; row < 32; ++row) {
    float a = 0.f;
    #pragma unroll
    for (int k = 0; k < 36; ++k) a += w[k] * xs[row][k];
    u16 h = f2h(a);
    y[(long)(r0 + row) * 256 + t] = h;
    float av = h2f(h);
    s1 += av; s2 += av * av;
  }
  atomicAdd(&st[t], s1);
  atomicAdd(&st[256 + t], s2);
}

// ---------- MFMA GEMM: 64M x 256N, phase-split, frag-major B, TPS taps/stage ----------
// R9 structure with TPS=2 tap-merge (24 stages: half the barrier convoys and
// per-stage fixed cost) and JIT per-stage B (no ping-pong reg sets).
// Stage s: pair p = s%NP, phase ph = s/NP (NP = L/TPS); 128B slices preserved
// (gather stays L2-resident per phase, the R5 win).
// Ledger (in-order vmcnt), per-stage issue: B(s)[TPS*KCP*2], idx(s+3)[<=1],
// dma(s+2)[TPS]; prologue: idx0,idx1,idx2 THEN dma(0),dma(1).
//  - stage-top vmcnt(2): younger-than-dma(s)-last >= 2 in every stage (incl.
//    s=0 and s=NS-2) -> retires dma(s); dma(s+1) is among the 2 youngest ->
//    always survives. Last stage: vmcnt(0).
//  - B(s) consumption auto-waits retire dma(s+1) (older) - it has had a full
//    stage to land, near-zero stall (R7: depth-2 vs 1 was only +2.7%).
//  - dma(s+2) targets buf bD whose readers finished before this stage's
//    barrier -> safe (3 rotating buffers).
template<int CT, int TPS>
__global__ __launch_bounds__(512, 4) void gemm3_k(
    const u16* __restrict__ P0, const u16* __restrict__ P1, int lda,
    const int* __restrict__ sp, int L,
    const u16* __restrict__ Wt, long wstride,
    u16* __restrict__ Yb, const float* __restrict__ bias, int Ostore,
    float* __restrict__ stats)
{
  constexpr int KC   = CT >> 5;            // k-chunks (32 elems) per tap
  constexpr int PH   = (CT == 256) ? 4 : 2;// phases -> 64-elem slice always
  constexpr int KCP  = KC / PH;            // k-chunks per tap per stage = 2
  constexpr int PROW = 64;                 // elems per row per stage-slice (128B)
  constexpr int BUFE = 64 * PROW;          // 8KB per-tap buffer (u16 elems)
  constexpr int SBUF = TPS * BUFE;         // stage buffer
  constexpr int NB   = TPS * KCP * 2;      // B fragments per stage (8 or 4)
  __shared__ __align__(16) u16 lA[3 * SBUF];
  const int tid  = threadIdx.x;
  const int wave = tid >> 6, lane = tid & 63;
  const int wn = wave * 32;                // N-split-8: 32 cols per wave
  const int lr = lane & 15, lq = lane >> 4;
  // XCD-aware bijective swizzle (nwg % 8 == 0 for all call sites)
  const int nwg = gridDim.x;
  const int wg = (blockIdx.x & 7) * (nwg >> 3) + (blockIdx.x >> 3);
  const int bm = wg * 64;
  const int batch = bm >> 14;
  const int vbase = bm & (V_N - 1);
  const int qrow = lane >> 3;              // row within DMA instr (8 rows/instr)
  const int qchunk = lane & 7;             // 16B chunk within 128B slice
  const bool gat = (sp != nullptr);
  const long rowb = (long)batch * V_N;     // gather row base (rows)
  const u16* Pd1 = P1 ? P1 : P0;
  const u16* Wb = Wt + (long)batch * wstride;
  const int NP = L / TPS;                  // tap-pairs per phase
  const int NS = PH * NP;                  // total stages

  // frag-major B pointers (64 lanes of one instr -> contiguous 1KB)
  const u16* bp[2];
  #pragma unroll
  for (int nt = 0; nt < 2; ++nt)
    bp[nt] = Wb + ((long)(wn + nt * 16 + lr) * 4 + lq) * 8;

  // lane-constant A-read element offsets (per 8KB tap buffer)
  int aOff[4][2];
  #pragma unroll
  for (int mt = 0; mt < 4; ++mt)
    #pragma unroll
    for (int kp = 0; kp < 2; ++kp) {
      int row = mt * 16 + lr;
      aOff[mt][kp] = row * PROW + (((kp * 4 + lq) ^ (row & 7)) << 3);
    }

  // idx for a pair: lanes [0,8*TPS) hold tap (p*TPS + lane>>3), row (lane&7)
  auto load_idxp = [&](int p) -> int {
    int v = 0;
    if (gat && lane < 8 * TPS) {
      int t = p * TPS + (lane >> 3);
      v = sp[(long)t * V_N + vbase + wave * 8 + (lane & 7)];
    }
    return v;
  };

  // stage DMA: TPS taps x 64 rows x 128B slice (TPS instrs per wave)
  auto dma_pair = [&](u16* buf, int p, int ph, int idxreg) {
    #pragma unroll
    for (int i = 0; i < TPS; ++i) {
      const u16* src = gat ? P0 : ((p * TPS + i) > 0 ? Pd1 : P0);
      u16* wb = buf + i * BUFE + wave * (8 * PROW);
      int rloc = wave * 8 + qrow;
      long grow;
      if (gat) grow = rowb + (long)__shfl(idxreg, i * 8 + qrow, 64);
      else     grow = bm + rloc;
      const u16* gp = src + grow * lda + ph * PROW + ((qchunk ^ (rloc & 7)) << 3);
      dma16(gp, wb);
    }
  };

  f32x4 acc[4][2];
  #pragma unroll
  for (int i = 0; i < 4; ++i)
    #pragma unroll
    for (int j = 0; j < 2; ++j) acc[i][j] = (f32x4){0.f, 0.f, 0.f, 0.f};

  // ---- prologue: idx pairs 0,1,2 FIRST (ledger), then dma(0), dma(1) ----
  int idxN;
  {
    int i0 = load_idxp(0);
    int i1 = load_idxp(1 % NP);
    idxN   = load_idxp(2 % NP);
    __builtin_amdgcn_sched_barrier(0);
    dma_pair(lA, 0, 0, i0);
    if (NS > 1) dma_pair(lA + SBUF, 1 % NP, 1 / NP, i1);
    __builtin_amdgcn_sched_barrier(0);
  }

  // rolling descriptors: (pC,phC)=stage s, (pD,phD)=stage s+2, pI=pair(s+3)
  int pC = 0, phC = 0;
  int pD = 2 % NP, phD = 2 / NP;
  int pI = 3 % NP;
  int bC = 0, bD = 2;                      // rotating buffer indices

  for (int s = 0; s < NS; ++s) {
    if (s + 1 < NS) asm volatile("s_waitcnt vmcnt(2)" ::: "memory");
    else            asm volatile("s_waitcnt vmcnt(0)" ::: "memory");
    asm volatile("s_waitcnt lgkmcnt(0)" ::: "memory");
    __builtin_amdgcn_s_barrier();
    __builtin_amdgcn_sched_barrier(0);
    // G0: JIT B(s) loads (older than this stage's dma -> no gather coupling)
    f16x8 tB[NB];
    #pragma unroll
    for (int i = 0; i < TPS; ++i)
      #pragma unroll
      for (int kp = 0; kp < KCP; ++kp)
        #pragma unroll
        for (int nt = 0; nt < 2; ++nt)
          tB[(i * KCP + kp) * 2 + nt] =
            *(const f16x8*)(bp[nt] + (long)((pC * TPS + i) * KC + phC * KCP + kp) * 8192);
    __builtin_amdgcn_sched_barrier(0);
    // G1: idx(pair s+3) + dma(s+2)
    int idxT = 0;
    if (gat && s + 3 < NS) idxT = load_idxp(pI);
    if (s + 2 < NS) dma_pair(lA + bD * SBUF, pD, phD, idxN);
    __builtin_amdgcn_sched_barrier(0);
    // per-tap interleaved compute: {A reads} | {MFMA} ...
    #pragma unroll
    for (int i = 0; i < TPS; ++i) {
      const int toff = bC * SBUF + i * BUFE;
      #pragma unroll
      for (int kp = 0; kp < KCP; ++kp) {
        f16x8 a[4];
        #pragma unroll
        for (int mt = 0; mt < 4; ++mt)
          a[mt] = *(const f16x8*)(lA + toff + aOff[mt][kp]);
        __builtin_amdgcn_sched_barrier(0);
        __builtin_amdgcn_s_setprio(1);
        #pragma unroll
        for (int mt = 0; mt < 4; ++mt) {
          acc[mt][0] = __builtin_amdgcn_mfma_f32_16x16x32_f16(a[mt], tB[(i * KCP + kp) * 2 + 0], acc[mt][0], 0, 0, 0);
          acc[mt][1] = __builtin_amdgcn_mfma_f32_16x16x32_f16(a[mt], tB[(i * KCP + kp) * 2 + 1], acc[mt][1], 0, 0, 0);
        }
        __builtin_amdgcn_s_setprio(0);
        __builtin_amdgcn_sched_barrier(0);
      }
    }
    // advance descriptors
    if (++pC == NP) { pC = 0; ++phC; }
    if (++pD == NP) { pD = 0; ++phD; }
    if (++pI == NP) { pI = 0; }
    bC = (bC == 2) ? 0 : bC + 1;
    bD = (bD == 2) ? 0 : bD + 1;
    idxN = idxT;
  }

  // epilogue: C/D layout col=lane&15, row=(lane>>4)*4+reg [guide m89]; fused stats
  #pragma unroll
  for (int nt = 0; nt < 2; ++nt) {
    int col = wn + nt * 16 + lr;
    if (col < Ostore) {
      float bv = bias ? bias[col] : 0.f;
      float s1 = 0.f, s2 = 0.f;
      #pragma unroll
      for (int mt = 0; mt < 4; ++mt) {
        #pragma unroll
        for (int rg = 0; rg < 4; ++rg) {
          int row = bm + mt * 16 + lq * 4 + rg;
          float v = acc[mt][nt][rg] + bv;
          Yb[(long)row * Ostore + col] = f2h(v);
          s1 += v; s2 += v * v;
        }
      }
      if (stats) {
        s1 += __shfl_xor(s1, 16); s1 += __shfl_xor(s1, 32);
        s2 += __shfl_xor(s2, 16); s2 += __shfl_xor(s2, 32);
        if (lq == 0) {
          atomicAdd(&stats[col], s1);
          atomicAdd(&stats[Ostore + col], s2);
        }
      }
    }
  }
}

// ---------- vectorized BN+ReLU (+residual/scale) (+SE sums) (+fused SE gate) ----------
// If sw1 != null: last block per batch (arrival counter cnt[b]) computes the
// SE gate sig[b*256+t] in-block after a release/acquire fence pair.
__global__ __launch_bounds__(256) void bnrelu2_k(
    const u16* __restrict__ y, const float* __restrict__ st,
    const float* __restrict__ g, const float* __restrict__ be,
    const u16* __restrict__ resid, const float* __restrict__ rscale,
    u16* __restrict__ ob, float* __restrict__ ses, int O,
    const float* __restrict__ sw1, const float* __restrict__ sw2,
    float* __restrict__ sig, int* __restrict__ cnt)
{
  __shared__ float sL[256];
  __shared__ float hh[32];
  __shared__ int lastFlag;
  int tid = threadIdx.x;
  int tpr = O >> 2;
  int rpi = 256 / tpr;
  int ci = (tid & (tpr - 1)) * 4;
  int row0 = blockIdx.x * (rpi * 16);
  int r0 = row0 + (tid / tpr);
  int b = row0 >> 14;
  float mean[4], sc[4], sh[4], rs[4];
  #pragma unroll
  for (int j = 0; j < 4; ++j) {
    int c = ci + j;
    float m = st[c] * (1.f / 32768.f);
    float var = st[O + c] * (1.f / 32768.f) - m * m;
    mean[j] = m;
    sc[j] = rsqrtf(fmaxf(var, 0.f) + 1e-5f) * g[c];
    sh[j] = be[c];
    rs[j] = rscale ? rscale[b * 256 + c] : 1.f;
  }
  float ss[4] = {0,0,0,0};
  for (int it = 0; it < 16; ++it) {
    long i = ((long)r0 + (long)it * rpi) * O + ci;
    uint2 pv = *(const uint2*)(y + i);
    float v[4];
    v[0] = fmaxf((h2f((u16)(pv.x & 0xffff)) - mean[0]) * sc[0] + sh[0], 0.f);
    v[1] = fmaxf((h2f((u16)(pv.x >> 16))    - mean[1]) * sc[1] + sh[1], 0.f);
    v[2] = fmaxf((h2f((u16)(pv.y & 0xffff)) - mean[2]) * sc[2] + sh[2], 0.f);
    v[3] = fmaxf((h2f((u16)(pv.y >> 16))    - mean[3]) * sc[3] + sh[3], 0.f);
    if (resid) {
      uint2 rv = *(const uint2*)(resid + i);
      v[0] += h2f((u16)(rv.x & 0xffff)) * rs[0]; v[1] += h2f((u16)(rv.x >> 16)) * rs[1];
      v[2] += h2f((u16)(rv.y & 0xffff)) * rs[2]; v[3] += h2f((u16)(rv.y >> 16)) * rs[3];
    }
    uint2 pk;
    pk.x = (unsigned)f2h(v[0]) | ((unsigned)f2h(v[1]) << 16);
    pk.y = (unsigned)f2h(v[2]) | ((unsigned)f2h(v[3]) << 16);
    *(uint2*)(ob + i) = pk;
    #pragma unroll
    for (int j = 0; j < 4; ++j) ss[j] += v[j];
  }
  if (ses) {
    sL[tid] = 0.f;
    __syncthreads();
    #pragma unroll
    for (int j = 0; j < 4; ++j) atomicAdd(&sL[ci + j], ss[j]);
    __syncthreads();
    atomicAdd(&ses[b * O + tid], sL[tid]);
    if (sw1) {
      __threadfence();                              // release our sesum adds
      __syncthreads();
      if (tid == 0) {
        int r = atomicAdd(&cnt[b], 1);
        lastFlag = (r == 255);                      // 256 blocks per batch
      }
      __syncthreads();
      if (lastFlag) {
        __threadfence();                            // acquire others' adds
        sL[tid] = ses[b * 256 + tid] * (1.f / 16384.f);
        __syncthreads();
        if (tid < 32) {
          float a = 0.f;
          for (int c = 0; c < 256; ++c) a += sw1[tid * 256 + c] * sL[c];
          hh[tid] = fmaxf(a, 0.f);
        }
        __syncthreads();
        float a = 0.f;
        #pragma unroll
        for (int r = 0; r < 32; ++r) a += sw2[tid * 32 + r] * hh[r];
        sig[b * 256 + tid] = 1.f / (1.f + expf(-a));
      }
    }
  }
}

// ---------- final head ----------
__global__ __launch_bounds__(256) void cls3_k(const u16* __restrict__ h2, const float* __restrict__ w,
                                              const float* __restrict__ b, float* __restrict__ out)
{
  __shared__ float ws[64];
  int t = threadIdx.x;
  if (t < 64) ws[t] = w[t];
  __syncthreads();
  int r = blockIdx.x * 256 + t;
  const u16* p = h2 + (long)r * 64;
  float a = b[0];
  #pragma unroll
  for (int c = 0; c < 64; ++c) a += ws[c] * h2f(p[c]);
  out[r] = a;
}

extern "C" void kernel_launch(void* const* d_in, const int* in_sizes, int n_in,
                              void* d_out, int out_size, void* d_ws, size_t ws_size,
                              hipStream_t stream)
{
  (void)in_sizes; (void)n_in; (void)out_size; (void)ws_size;
  const float* verts   = (const float*)d_in[0];
  const int*   spirals = (const int*)d_in[1];
  const float* enc0_w  = (const float*)d_in[2];
  const float* enc0_g  = (const float*)d_in[4];
  const float* enc0_be = (const float*)d_in[5];
  const float* enc_w   = (const float*)d_in[6];
  const float* enc_g   = (const float*)d_in[8];
  const float* enc_be  = (const float*)d_in[9];
  const float* se_w1   = (const float*)d_in[10];
  const float* se_w2   = (const float*)d_in[11];
  const float* skip_w  = (const float*)d_in[12];
  const float* skip_b  = (const float*)d_in[13];
  const float* dec_w   = (const float*)d_in[14];
  const float* dec_g   = (const float*)d_in[16];
  const float* dec_be  = (const float*)d_in[17];
  const float* cls1_w  = (const float*)d_in[18];
  const float* cls1_g  = (const float*)d_in[20];
  const float* cls1_be = (const float*)d_in[21];
  const float* cls2_w  = (const float*)d_in[22];
  const float* cls2_g  = (const float*)d_in[24];
  const float* cls2_be = (const float*)d_in[25];
  const float* cls3_w  = (const float*)d_in[26];
  const float* cls3_b  = (const float*)d_in[27];

  // --- workspace (~118 MB) ---
  char* p = (char*)d_ws;
  auto alloc = [&](size_t n) { char* q = p; p += (n + 255) & ~(size_t)255; return q; };
  u16* wpe     = (u16*)alloc((size_t)6 * 256 * 3072 * 2);       // 6 permuted conv weights
  u16* wpe_s   = (u16*)alloc((size_t)3 * 2 * 256 * 3072 * 2);   // enc, per-batch SE-folded
  u16* skip_wb = (u16*)alloc((size_t)3 * 256 * 512 * 2);
  u16* skip_s  = (u16*)alloc((size_t)3 * 2 * 256 * 512 * 2);    // skip, per-batch folded
  u16* cls1_wb = (u16*)alloc((size_t)256 * 256 * 2);            // zero-padded to 256 cols
  u16* wp6     = (u16*)alloc((size_t)256 * 128 * 2);            // zero-padded to 256 cols
  // zeroed region: 10 stats slots + 4 sesum slots + counters (one memset)
  float* stats = (float*)alloc(10 * 2048);                      // slot i = stats + i*512
  float* sesum = (float*)alloc(4 * 2048);                       // slot i = sesum + i*512
  int*   cnt   = (int*)alloc(256);                              // stage i -> cnt + i*2
  float* sig   = (float*)alloc(4 * 2048);                       // sig_i = sig + i*512
  u16* out0 = (u16*)alloc((size_t)M_N * 256 * 2);
  u16* out1 = (u16*)alloc((size_t)M_N * 256 * 2);
  u16* out2 = (u16*)alloc((size_t)M_N * 256 * 2);
  u16* ct   = (u16*)alloc((size_t)M_N * 256 * 2);               // conv temp; aliases out3
  u16* tb   = (u16*)alloc((size_t)M_N * 256 * 2);
  u16* xd   = (u16*)alloc((size_t)M_N * 256 * 2);
  u16* outs[4] = {out0, out1, out2, ct};
  const size_t WENC = (size_t)256 * 3072;      // elems per enc weight copy
  const size_t WSKP = (size_t)256 * 512;

  // single upfront zero of stats+sesum+cnt (contiguous allocs, 256-aligned)
  hipMemsetAsync(stats, 0, 10 * 2048 + 4 * 2048 + 256, stream);

  // prep (all weights -> fragment-major)
  perm2_k<<<768, 256, 0, stream>>>(enc_w, wpe);
  perm2_k<<<768, 256, 0, stream>>>(dec_w, wpe + (size_t)3 * WENC);
  for (int s = 0; s < 3; ++s)
    permfr_k<<<512, 256, 0, stream>>>(skip_w + (size_t)s * 256 * 512,
                                      skip_wb + (size_t)s * WSKP, 256, 512);
  permfr_k<<<256, 256, 0, stream>>>(cls1_w, cls1_wb, 128, 256);
  permfr_k<<<128, 256, 0, stream>>>(cls2_w, wp6, 64, 128);

  // ---- encoder block 0 (stats fused into enc0; SE gate fused into bnrelu) ----
  enc0_k<<<1024, 256, 0, stream>>>(verts, spirals, enc0_w, ct, stats);
  bnrelu2_k<<<512, 256, 0, stream>>>(ct, stats, enc0_g, enc0_be, nullptr, nullptr,
                                     out0, sesum, 256, se_w1, se_w2, sig, cnt);

  // ---- encoder blocks 1..3 (SE scale folded into per-batch weights) ----
  for (int i = 1; i < 4; ++i) {
    wscale_k<<<3072, 256, 0, stream>>>(wpe + (size_t)(i - 1) * WENC, sig + (i - 1) * 512, nullptr,
                                       wpe_s + (size_t)(i - 1) * 2 * WENC, (int)WENC, 255);
    gemm3_k<256, 2><<<512, 512, 0, stream>>>(outs[i - 1], nullptr, 256,
                                             spirals + (size_t)i * V_N * 12, 12,
                                             wpe_s + (size_t)(i - 1) * 2 * WENC, (long)WENC,
                                             ct, nullptr, 256, stats + i * 512);
    bnrelu2_k<<<512, 256, 0, stream>>>(ct, stats + i * 512, enc_g + (i - 1) * 256, enc_be + (i - 1) * 256,
                                       outs[i - 1], sig + (i - 1) * 512, outs[i], sesum + i * 512, 256,
                                       se_w1 + (size_t)i * 32 * 256, se_w2 + (size_t)i * 256 * 32,
                                       sig + i * 512, cnt + i * 2);
  }

  // ---- decoder blocks (decoder input SE-scale folded into skip weights at i=0) ----
  for (int i = 0; i < 3; ++i) {
    wscale_k<<<512, 256, 0, stream>>>(skip_wb + (size_t)i * WSKP, sig + (2 - i) * 512,
                                      (i == 0) ? (sig + 3 * 512) : nullptr,
                                      skip_s + (size_t)i * 2 * WSKP, (int)WSKP, 511);
    gemm3_k<256, 2><<<512, 512, 0, stream>>>((i == 0) ? ct : xd, outs[2 - i], 256, nullptr, 2,
                                             skip_s + (size_t)i * 2 * WSKP, (long)WSKP,
                                             tb, skip_b + i * 256, 256, nullptr);     // x1 -> tb
    gemm3_k<256, 2><<<512, 512, 0, stream>>>(tb, nullptr, 256,
                                             spirals + (size_t)(2 - i) * V_N * 12, 12,
                                             wpe + (size_t)(3 + i) * WENC, 0,
                                             outs[2 - i], nullptr, 256, stats + (4 + i) * 512);
    bnrelu2_k<<<512, 256, 0, stream>>>(outs[2 - i], stats + (4 + i) * 512, dec_g + i * 256, dec_be + i * 256,
                                       tb, nullptr, xd, nullptr, 256,
                                       nullptr, nullptr, nullptr, nullptr);            // x -> xd
  }

  // ---- classifier ----
  gemm3_k<256, 1><<<512, 512, 0, stream>>>(xd, nullptr, 256, nullptr, 1,
                                           cls1_wb, 0, ct, nullptr, 128, stats + 7 * 512);
  bnrelu2_k<<<256, 256, 0, stream>>>(ct, stats + 7 * 512, cls1_g, cls1_be, nullptr, nullptr,
                                     ct, nullptr, 128, nullptr, nullptr, nullptr, nullptr);
  gemm3_k<128, 1><<<512, 512, 0, stream>>>(ct, nullptr, 128, nullptr, 1,
                                           wp6, 0, tb, nullptr, 64, stats + 8 * 512);
  bnrelu2_k<<<128, 256, 0, stream>>>(tb, stats + 8 * 512, cls2_g, cls2_be, nullptr, nullptr,
                                     tb, nullptr, 64, nullptr, nullptr, nullptr, nullptr);
  cls3_k<<<128, 256, 0, stream>>>(tb, cls3_w, cls3_b, (float*)d_out);
}

// Round 11
// 883.738 us; speedup vs baseline: 1.5752x; 1.5752x over previous
//
#include <hip/hip_runtime.h>

typedef unsigned short u16;
using f16x8 = __attribute__((ext_vector_type(8))) _Float16;  // 8 fp16 (4 VGPRs)
using f32x4 = __attribute__((ext_vector_type(4))) float;

#define V_N 16384
#define M_N 32768

__device__ __forceinline__ float h2f(u16 u) {
  _Float16 h; __builtin_memcpy(&h, &u, 2); return (float)h;
}
__device__ __forceinline__ u16 f2h(float f) {
  _Float16 h = (_Float16)f; u16 u; __builtin_memcpy(&u, &h, 2); return u;
}

// async global->LDS DMA, 16B per lane; LDS dest = wave-uniform base + lane*16
__device__ __forceinline__ void dma16(const u16* g, u16* l) {
  __builtin_amdgcn_global_load_lds(
      (const __attribute__((address_space(1))) void*)(const void*)g,
      (__attribute__((address_space(3))) void*)(void*)l, 16, 0, 0);
}

// ---------- prep kernels ----------
// Weight permute to FRAGMENT-MAJOR: dst[kc][col][lq][j] (kc = k>>5, lq=(k>>3)&3,
// j=k&7, k = tap*256 + c). One B-load instr = contiguous 1KB (R5/R6 lesson:
// col-strided fragments = 64 scattered lines/instr -> TA serialization).
__global__ __launch_bounds__(256) void perm2_k(const float* __restrict__ w, u16* __restrict__ wp) {
  int o = blockIdx.x & 255, layer = blockIdx.x >> 8;
  int t = threadIdx.x;                       // t = input channel c
  const float* src = w + ((size_t)layer * 256 + o) * 3072;
  u16* dst = wp + (size_t)layer * 786432;    // frag-major layer base
  float2 v[6];
  #pragma unroll
  for (int q = 0; q < 6; ++q) v[q] = *(const float2*)(src + t * 12 + q * 2);
  const float* vf = (const float*)v;         // vf[m] = w[o][c=t, tap=m]
  int lo = t & 31;                           // (k&31) = lq*8+j
  #pragma unroll
  for (int m = 0; m < 12; ++m) {
    int kc = m * 8 + (t >> 5);               // k = m*256 + t
    dst[(size_t)kc * 8192 + o * 32 + lo] = f2h(vf[m]);
  }
}

// generic f32 [O][K] row-major -> frag-major fp16 [kc][256][lq][j], zero-pad col>=O
__global__ __launch_bounds__(256) void permfr_k(const float* __restrict__ src, u16* __restrict__ dst,
                                                int O, int K) {
  int i = blockIdx.x * 256 + threadIdx.x;
  if (i >= (K << 8)) return;
  int j = i & 7, lq = (i >> 3) & 3, col = (i >> 5) & 255, kc = i >> 13;
  int k = kc * 32 + lq * 8 + j;
  float v = (col < O) ? src[(size_t)col * K + k] : 0.f;
  dst[i] = f2h(v);
}

// per-batch SE-scale fold into frag-major weights
__global__ __launch_bounds__(256) void wscale_k(const u16* __restrict__ w, const float* __restrict__ sig,
                                                const float* __restrict__ sigx,
                                                u16* __restrict__ o, int n, int sel) {
  int i = blockIdx.x * 256 + threadIdx.x;
  if (i >= n) return;
  float wv = h2f(w[i]);
  int k = (i >> 13) * 32 + ((i >> 3) & 3) * 8 + (i & 7);
  int c = k & 255;
  #pragma unroll
  for (int b = 0; b < 2; ++b) {
    float s;
    if (sel == 511 && k < 256) s = sigx ? sigx[b * 256 + c] : 1.f;
    else                       s = sig[b * 256 + c];
    o[(long)b * n + i] = f2h(wv * s);
  }
}

// ---------- encoder block 0 conv (C_in=3, K=36) + FUSED channel stats ----------
__global__ __launch_bounds__(256) void enc0_k(const float* __restrict__ verts, const int* __restrict__ sp,
                                              const float* __restrict__ w0, u16* __restrict__ y,
                                              float* __restrict__ st) {
  __shared__ float xs[32][36];
  int t = threadIdx.x;
  int r0 = blockIdx.x * 32;
  for (int s = t; s < 32 * 12; s += 256) {
    int row = s / 12, tt = s - row * 12;
    int gr = r0 + row;
    int b = gr >> 14, v = gr & (V_N - 1);
    int j = sp[tt * V_N + v];
    const float* p = verts + ((long)b * V_N + j) * 3;
    xs[row][tt]      = p[0];
    xs[row][12 + tt] = p[1];
    xs[row][24 + tt] = p[2];
  }
  __syncthreads();
  float w[36];
  #pragma unroll
  for (int k = 0; k < 36; ++k) w[k] = w0[t * 36 + k];
  float s1 = 0.f, s2 = 0.f;
  for (int row = 0; row < 32; ++row) {
    float a = 0.f;
    #pragma unroll
    for (int k = 0; k < 36; ++k) a += w[k] * xs[row][k];
    u16 h = f2h(a);
    y[(long)(r0 + row) * 256 + t] = h;
    float av = h2f(h);
    s1 += av; s2 += av * av;
  }
  atomicAdd(&st[t], s1);
  atomicAdd(&st[256 + t], s2);
}

// ---------- MFMA GEMM: 64M x 256N, phase-split, frag-major B, interleaved stage ----------
// R9 proven structure (84 us/conv): depth-2 counted-vmcnt, 3x8KB buffers,
// ping-pong B register sets (tA/tB2, unroll-2, rule #20), intra-stage pipe
// interleave ({A kp0 + B kp0}|{MFMA}|{idx+dma}|{A kp1 + B kp1}|{MFMA}),
// setprio(1) around MFMA groups (T5).
// Ledger (in-order vmcnt), per-stage issue: lB0,lB1,idx,dma(s+2),lB2,lB3.
//  - ops younger than dma(s+2) = 2 (<=4) -> survives stage-top vmcnt(5).
//  - dma(s) retires during stage s-1's compiler auto-waits (6 younger ops),
//    before the stage-s barrier -> buffer s%3 safe to read.
//  - dma(s+2) writes buf (s-1)%3, whose readers finished before the stage-s
//    barrier that precedes the dma issue -> safe.
// R10 lesson (do NOT revisit): TPS=2 + JIT per-stage B spills tB to scratch
// (VGPR cap 128 at 4 waves/SIMD) -> WRITE_SIZE 17->49MB, conv 84->142us.
template<int CT>
__global__ __launch_bounds__(512, 4) void gemm3_k(
    const u16* __restrict__ P0, const u16* __restrict__ P1, int lda,
    const int* __restrict__ sp, int L,
    const u16* __restrict__ Wt, long wstride,
    u16* __restrict__ Yb, const float* __restrict__ bias, int Ostore,
    float* __restrict__ stats)
{
  constexpr int KC   = CT >> 5;            // k-chunks (32 elems) per tap (8 or 4)
  constexpr int PH   = (CT == 256) ? 4 : 2;// phases -> 64-elem slice always
  constexpr int KCP  = KC / PH;            // k-chunks per stage = 2
  constexpr int PROW = 64;                 // elems per row per stage (128B)
  constexpr int BUFE = 64 * PROW;          // 8KB buffer (u16 elems)
  __shared__ __align__(16) u16 lA[3 * BUFE];   // 3 stage buffers (24KB)
  const int tid  = threadIdx.x;
  const int wave = tid >> 6, lane = tid & 63;
  const int wn = wave * 32;                // N-split-8: 32 cols per wave
  const int lr = lane & 15, lq = lane >> 4;
  // XCD-aware bijective swizzle (nwg % 8 == 0 for all call sites)
  const int nwg = gridDim.x;
  const int wg = (blockIdx.x & 7) * (nwg >> 3) + (blockIdx.x >> 3);
  const int bm = wg * 64;
  const int batch = bm >> 14;
  const int vbase = bm & (V_N - 1);
  const int qrow = lane >> 3;              // row within DMA instr (8 rows/instr)
  const int qchunk = lane & 7;             // 16B chunk within 128B slice
  const bool gat = (sp != nullptr);
  const long rowb = (long)batch * V_N;     // gather row base (rows)
  const u16* Pd1 = P1 ? P1 : P0;
  const u16* Wb = Wt + (long)batch * wstride;
  const int NS = PH * L;                   // total stages (even)

  // frag-major B pointers: fragment (col=wn+nt*16+lr, half lq) of kchunk kc at
  // Wb + kc*8192 + col*32 + lq*8  (64 lanes of one instr -> contiguous 1KB)
  const u16* bp[2];
  #pragma unroll
  for (int nt = 0; nt < 2; ++nt)
    bp[nt] = Wb + ((long)(wn + nt * 16 + lr) * 4 + lq) * 8;

  // lane-constant A-read addresses (elems from lA base); per-stage cost = +bufoff
  const u16* aBase[4][2];
  #pragma unroll
  for (int mt = 0; mt < 4; ++mt)
    #pragma unroll
    for (int kp = 0; kp < 2; ++kp) {
      int row = mt * 16 + lr;
      aBase[mt][kp] = lA + row * PROW + (((kp * 4 + lq) ^ (row & 7)) << 3);
    }

  auto load_idx = [&](int tap) -> int {
    int v = 0;
    if (gat && lane < 8) v = sp[(long)tap * V_N + vbase + wave * 8 + lane];
    return v;
  };

  // stage DMA: 64 rows x 128B slice; wave w covers rows [w*8, w*8+8), 1 instr
  auto dma_st = [&](u16* buf, const u16* src, int idxreg, int ph) {
    u16* wb = buf + wave * (8 * PROW);
    int rloc = wave * 8 + qrow;
    long grow;
    if (gat) grow = rowb + (long)__shfl(idxreg, qrow, 64);
    else     grow = bm + rloc;
    const u16* gp = src + grow * lda + ph * PROW + ((qchunk ^ (rloc & 7)) << 3);
    dma16(gp, wb);
  };

  f32x4 acc[4][2];
  #pragma unroll
  for (int i = 0; i < 4; ++i)
    #pragma unroll
    for (int j = 0; j < 2; ++j) acc[i][j] = (f32x4){0.f, 0.f, 0.f, 0.f};

  f16x8 tA[KCP * 2], tB2[KCP * 2];

  // rolling stage descriptors: (lB,phB)=stage s+1, (lD,phD)=stage s+2, lI=tap(s+3)
  auto adv = [&](int& l, int& ph) { if (++l == L) { l = 0; ++ph; } };
  int lB = 0, phB = 0; adv(lB, phB);
  int lD = lB, phD = phB; adv(lD, phD);
  int lI = lD; { int pT = phD; int lT = lI; adv(lT, pT); lI = lT; }
  int idxN;   // idx for the dma issued at the CURRENT stage (stage s -> dma(s+2))

  // ---- prologue: idx(tap0,tap1,tap2); dma(0); dma(1); loadB(0) ----
  {
    int i0 = load_idx(0);
    int i1 = load_idx(lB);
    idxN = load_idx(lD);
    dma_st(lA, P0, i0, 0);
    if (NS > 1) {
      const u16* s1 = (!gat && lB > 0) ? Pd1 : P0;
      dma_st(lA + BUFE, s1, i1, phB);
    }
    __builtin_amdgcn_sched_barrier(0);
    #pragma unroll
    for (int kp = 0; kp < KCP; ++kp)
      #pragma unroll
      for (int nt = 0; nt < 2; ++nt)
        tA[kp * 2 + nt] = *(const f16x8*)(bp[nt] + (long)kp * 8192);
    __builtin_amdgcn_sched_barrier(0);
  }

  auto stage = [&](int s, f16x8 (&tCur)[KCP * 2], f16x8 (&tNxt)[KCP * 2]) {
    if (s + 1 < NS) asm volatile("s_waitcnt vmcnt(5)" ::: "memory");
    else            asm volatile("s_waitcnt vmcnt(0)" ::: "memory");
    asm volatile("s_waitcnt lgkmcnt(0)" ::: "memory");
    __builtin_amdgcn_s_barrier();
    __builtin_amdgcn_sched_barrier(0);
    const int so = (s % 3) * BUFE;
    const long cbB = (long)(lB * KC + phB * KCP);
    // group 1: A kp0 reads + B(s+1) kp0 half
    f16x8 a0[4];
    #pragma unroll
    for (int mt = 0; mt < 4; ++mt) a0[mt] = *(const f16x8*)(aBase[mt][0] + so);
    if (s + 1 < NS) {
      tNxt[0] = *(const f16x8*)(bp[0] + cbB * 8192);
      tNxt[1] = *(const f16x8*)(bp[1] + cbB * 8192);
    }
    __builtin_amdgcn_sched_barrier(0);
    // group 2: MFMA kp0
    __builtin_amdgcn_s_setprio(1);
    #pragma unroll
    for (int mt = 0; mt < 4; ++mt) {
      acc[mt][0] = __builtin_amdgcn_mfma_f32_16x16x32_f16(a0[mt], tCur[0], acc[mt][0], 0, 0, 0);
      acc[mt][1] = __builtin_amdgcn_mfma_f32_16x16x32_f16(a0[mt], tCur[1], acc[mt][1], 0, 0, 0);
    }
    __builtin_amdgcn_s_setprio(0);
    __builtin_amdgcn_sched_barrier(0);
    // group 3: idx + dma(s+2)
    int idxT = 0;
    if (gat && s + 3 < NS) idxT = load_idx(lI);
    if (s + 2 < NS) {
      const u16* srcD = (!gat && lD > 0) ? Pd1 : P0;
      dma_st(lA + ((s + 2) % 3) * BUFE, srcD, idxN, phD);
    }
    __builtin_amdgcn_sched_barrier(0);
    // group 4: A kp1 reads + B(s+1) kp1 half
    f16x8 a1[4];
    #pragma unroll
    for (int mt = 0; mt < 4; ++mt) a1[mt] = *(const f16x8*)(aBase[mt][1] + so);
    if (s + 1 < NS) {
      tNxt[2] = *(const f16x8*)(bp[0] + (cbB + 1) * 8192);
      tNxt[3] = *(const f16x8*)(bp[1] + (cbB + 1) * 8192);
    }
    __builtin_amdgcn_sched_barrier(0);
    // group 5: MFMA kp1
    __builtin_amdgcn_s_setprio(1);
    #pragma unroll
    for (int mt = 0; mt < 4; ++mt) {
      acc[mt][0] = __builtin_amdgcn_mfma_f32_16x16x32_f16(a1[mt], tCur[2], acc[mt][0], 0, 0, 0);
      acc[mt][1] = __builtin_amdgcn_mfma_f32_16x16x32_f16(a1[mt], tCur[3], acc[mt][1], 0, 0, 0);
    }
    __builtin_amdgcn_s_setprio(0);
    adv(lB, phB); adv(lD, phD); if (++lI == L) lI = 0;
    idxN = idxT;
  };

  for (int s = 0; s < NS; s += 2) {
    stage(s, tA, tB2);
    stage(s + 1, tB2, tA);
  }

  // epilogue: C/D layout col=lane&15, row=(lane>>4)*4+reg [guide m89]; fused stats
  #pragma unroll
  for (int nt = 0; nt < 2; ++nt) {
    int col = wn + nt * 16 + lr;
    if (col < Ostore) {
      float bv = bias ? bias[col] : 0.f;
      float s1 = 0.f, s2 = 0.f;
      #pragma unroll
      for (int mt = 0; mt < 4; ++mt) {
        #pragma unroll
        for (int rg = 0; rg < 4; ++rg) {
          int row = bm + mt * 16 + lq * 4 + rg;
          float v = acc[mt][nt][rg] + bv;
          Yb[(long)row * Ostore + col] = f2h(v);
          s1 += v; s2 += v * v;
        }
      }
      if (stats) {
        s1 += __shfl_xor(s1, 16); s1 += __shfl_xor(s1, 32);
        s2 += __shfl_xor(s2, 16); s2 += __shfl_xor(s2, 32);
        if (lq == 0) {
          atomicAdd(&stats[col], s1);
          atomicAdd(&stats[Ostore + col], s2);
        }
      }
    }
  }
}

// ---------- vectorized BN+ReLU (+fp16 residual, optional per-channel resid scale) (+SE sums) ----------
__global__ __launch_bounds__(256) void bnrelu2_k(
    const u16* __restrict__ y, const float* __restrict__ st,
    const float* __restrict__ g, const float* __restrict__ be,
    const u16* __restrict__ resid, const float* __restrict__ rscale,
    u16* __restrict__ ob, float* __restrict__ ses, int O)
{
  __shared__ float sL[256];
  int tid = threadIdx.x;
  int tpr = O >> 2;
  int rpi = 256 / tpr;
  int ci = (tid & (tpr - 1)) * 4;
  int row0 = blockIdx.x * (rpi * 16);
  int r0 = row0 + (tid / tpr);
  int b = row0 >> 14;
  float mean[4], sc[4], sh[4], rs[4];
  #pragma unroll
  for (int j = 0; j < 4; ++j) {
    int c = ci + j;
    float m = st[c] * (1.f / 32768.f);
    float var = st[O + c] * (1.f / 32768.f) - m * m;
    mean[j] = m;
    sc[j] = rsqrtf(fmaxf(var, 0.f) + 1e-5f) * g[c];
    sh[j] = be[c];
    rs[j] = rscale ? rscale[b * 256 + c] : 1.f;
  }
  float ss[4] = {0,0,0,0};
  for (int it = 0; it < 16; ++it) {
    long i = ((long)r0 + (long)it * rpi) * O + ci;
    uint2 pv = *(const uint2*)(y + i);
    float v[4];
    v[0] = fmaxf((h2f((u16)(pv.x & 0xffff)) - mean[0]) * sc[0] + sh[0], 0.f);
    v[1] = fmaxf((h2f((u16)(pv.x >> 16))    - mean[1]) * sc[1] + sh[1], 0.f);
    v[2] = fmaxf((h2f((u16)(pv.y & 0xffff)) - mean[2]) * sc[2] + sh[2], 0.f);
    v[3] = fmaxf((h2f((u16)(pv.y >> 16))    - mean[3]) * sc[3] + sh[3], 0.f);
    if (resid) {
      uint2 rv = *(const uint2*)(resid + i);
      v[0] += h2f((u16)(rv.x & 0xffff)) * rs[0]; v[1] += h2f((u16)(rv.x >> 16)) * rs[1];
      v[2] += h2f((u16)(rv.y & 0xffff)) * rs[2]; v[3] += h2f((u16)(rv.y >> 16)) * rs[3];
    }
    uint2 pk;
    pk.x = (unsigned)f2h(v[0]) | ((unsigned)f2h(v[1]) << 16);
    pk.y = (unsigned)f2h(v[2]) | ((unsigned)f2h(v[3]) << 16);
    *(uint2*)(ob + i) = pk;
    #pragma unroll
    for (int j = 0; j < 4; ++j) ss[j] += v[j];
  }
  if (ses) {
    sL[tid] = 0.f;
    __syncthreads();
    #pragma unroll
    for (int j = 0; j < 4; ++j) atomicAdd(&sL[ci + j], ss[j]);
    __syncthreads();
    atomicAdd(&ses[b * O + tid], sL[tid]);
  }
}

// ---------- SE gate ----------
__global__ void se_k(const float* __restrict__ ses, const float* __restrict__ w1,
                     const float* __restrict__ w2, float* __restrict__ sig)
{
  __shared__ float s[256];
  __shared__ float h[32];
  int b = blockIdx.x, t = threadIdx.x;
  s[t] = ses[b * 256 + t] * (1.f / 16384.f);
  __syncthreads();
  if (t < 32) {
    float a = 0.f;
    for (int c = 0; c < 256; ++c) a += w1[t * 256 + c] * s[c];
    h[t] = fmaxf(a, 0.f);
  }
  __syncthreads();
  float a = 0.f;
  #pragma unroll
  for (int r = 0; r < 32; ++r) a += w2[t * 32 + r] * h[r];
  sig[b * 256 + t] = 1.f / (1.f + expf(-a));
}

// ---------- final head ----------
__global__ __launch_bounds__(256) void cls3_k(const u16* __restrict__ h2, const float* __restrict__ w,
                                              const float* __restrict__ b, float* __restrict__ out)
{
  __shared__ float ws[64];
  int t = threadIdx.x;
  if (t < 64) ws[t] = w[t];
  __syncthreads();
  int r = blockIdx.x * 256 + t;
  const u16* p = h2 + (long)r * 64;
  float a = b[0];
  #pragma unroll
  for (int c = 0; c < 64; ++c) a += ws[c] * h2f(p[c]);
  out[r] = a;
}

extern "C" void kernel_launch(void* const* d_in, const int* in_sizes, int n_in,
                              void* d_out, int out_size, void* d_ws, size_t ws_size,
                              hipStream_t stream)
{
  (void)in_sizes; (void)n_in; (void)out_size; (void)ws_size;
  const float* verts   = (const float*)d_in[0];
  const int*   spirals = (const int*)d_in[1];
  const float* enc0_w  = (const float*)d_in[2];
  const float* enc0_g  = (const float*)d_in[4];
  const float* enc0_be = (const float*)d_in[5];
  const float* enc_w   = (const float*)d_in[6];
  const float* enc_g   = (const float*)d_in[8];
  const float* enc_be  = (const float*)d_in[9];
  const float* se_w1   = (const float*)d_in[10];
  const float* se_w2   = (const float*)d_in[11];
  const float* skip_w  = (const float*)d_in[12];
  const float* skip_b  = (const float*)d_in[13];
  const float* dec_w   = (const float*)d_in[14];
  const float* dec_g   = (const float*)d_in[16];
  const float* dec_be  = (const float*)d_in[17];
  const float* cls1_w  = (const float*)d_in[18];
  const float* cls1_g  = (const float*)d_in[20];
  const float* cls1_be = (const float*)d_in[21];
  const float* cls2_w  = (const float*)d_in[22];
  const float* cls2_g  = (const float*)d_in[24];
  const float* cls2_be = (const float*)d_in[25];
  const float* cls3_w  = (const float*)d_in[26];
  const float* cls3_b  = (const float*)d_in[27];

  // --- workspace (~118 MB) ---
  char* p = (char*)d_ws;
  auto alloc = [&](size_t n) { char* q = p; p += (n + 255) & ~(size_t)255; return q; };
  u16* wpe     = (u16*)alloc((size_t)6 * 256 * 3072 * 2);       // 6 permuted conv weights
  u16* wpe_s   = (u16*)alloc((size_t)3 * 2 * 256 * 3072 * 2);   // enc, per-batch SE-folded
  u16* skip_wb = (u16*)alloc((size_t)3 * 256 * 512 * 2);
  u16* skip_s  = (u16*)alloc((size_t)3 * 2 * 256 * 512 * 2);    // skip, per-batch folded
  u16* cls1_wb = (u16*)alloc((size_t)256 * 256 * 2);            // zero-padded to 256 cols
  u16* wp6     = (u16*)alloc((size_t)256 * 128 * 2);            // zero-padded to 256 cols
  // zeroed region: 10 stats slots + 4 sesum slots (ONE upfront memset)
  float* stats = (float*)alloc(10 * 2048);                      // slot i = stats + i*512
  float* sesum = (float*)alloc(4 * 2048);                       // slot i = sesum + i*512
  float* sig   = (float*)alloc(4 * 2048);                       // sig_i = sig + i*512
  u16* out0 = (u16*)alloc((size_t)M_N * 256 * 2);
  u16* out1 = (u16*)alloc((size_t)M_N * 256 * 2);
  u16* out2 = (u16*)alloc((size_t)M_N * 256 * 2);
  u16* ct   = (u16*)alloc((size_t)M_N * 256 * 2);               // conv temp; aliases out3
  u16* tb   = (u16*)alloc((size_t)M_N * 256 * 2);
  u16* xd   = (u16*)alloc((size_t)M_N * 256 * 2);
  u16* outs[4] = {out0, out1, out2, ct};
  const size_t WENC = (size_t)256 * 3072;      // elems per enc weight copy
  const size_t WSKP = (size_t)256 * 512;

  // single upfront zero of stats+sesum (contiguous allocs, 256-aligned)
  hipMemsetAsync(stats, 0, 10 * 2048 + 4 * 2048, stream);

  // prep (all weights -> fragment-major)
  perm2_k<<<768, 256, 0, stream>>>(enc_w, wpe);
  perm2_k<<<768, 256, 0, stream>>>(dec_w, wpe + (size_t)3 * WENC);
  for (int s = 0; s < 3; ++s)
    permfr_k<<<512, 256, 0, stream>>>(skip_w + (size_t)s * 256 * 512,
                                      skip_wb + (size_t)s * WSKP, 256, 512);
  permfr_k<<<256, 256, 0, stream>>>(cls1_w, cls1_wb, 128, 256);
  permfr_k<<<128, 256, 0, stream>>>(cls2_w, wp6, 64, 128);

  // ---- encoder block 0 (stats fused into enc0) ----
  enc0_k<<<1024, 256, 0, stream>>>(verts, spirals, enc0_w, ct, stats);
  bnrelu2_k<<<512, 256, 0, stream>>>(ct, stats, enc0_g, enc0_be, nullptr, nullptr, out0, sesum, 256);
  se_k<<<2, 256, 0, stream>>>(sesum, se_w1, se_w2, sig);

  // ---- encoder blocks 1..3 (SE scale folded into per-batch weights) ----
  for (int i = 1; i < 4; ++i) {
    wscale_k<<<3072, 256, 0, stream>>>(wpe + (size_t)(i - 1) * WENC, sig + (i - 1) * 512, nullptr,
                                       wpe_s + (size_t)(i - 1) * 2 * WENC, (int)WENC, 255);
    gemm3_k<256><<<512, 512, 0, stream>>>(outs[i - 1], nullptr, 256,
                                          spirals + (size_t)i * V_N * 12, 12,
                                          wpe_s + (size_t)(i - 1) * 2 * WENC, (long)WENC,
                                          ct, nullptr, 256, stats + i * 512);
    bnrelu2_k<<<512, 256, 0, stream>>>(ct, stats + i * 512, enc_g + (i - 1) * 256, enc_be + (i - 1) * 256,
                                       outs[i - 1], sig + (i - 1) * 512, outs[i], sesum + i * 512, 256);
    se_k<<<2, 256, 0, stream>>>(sesum + i * 512, se_w1 + (size_t)i * 32 * 256,
                                se_w2 + (size_t)i * 256 * 32, sig + i * 512);
  }

  // ---- decoder blocks (decoder input SE-scale folded into skip weights at i=0) ----
  for (int i = 0; i < 3; ++i) {
    wscale_k<<<512, 256, 0, stream>>>(skip_wb + (size_t)i * WSKP, sig + (2 - i) * 512,
                                      (i == 0) ? (sig + 3 * 512) : nullptr,
                                      skip_s + (size_t)i * 2 * WSKP, (int)WSKP, 511);
    gemm3_k<256><<<512, 512, 0, stream>>>((i == 0) ? ct : xd, outs[2 - i], 256, nullptr, 2,
                                          skip_s + (size_t)i * 2 * WSKP, (long)WSKP,
                                          tb, skip_b + i * 256, 256, nullptr);       // x1 -> tb
    gemm3_k<256><<<512, 512, 0, stream>>>(tb, nullptr, 256,
                                          spirals + (size_t)(2 - i) * V_N * 12, 12,
                                          wpe + (size_t)(3 + i) * WENC, 0,
                                          outs[2 - i], nullptr, 256, stats + (4 + i) * 512);
    bnrelu2_k<<<512, 256, 0, stream>>>(outs[2 - i], stats + (4 + i) * 512, dec_g + i * 256, dec_be + i * 256,
                                       tb, nullptr, xd, nullptr, 256);                // x -> xd
  }

  // ---- classifier ----
  gemm3_k<256><<<512, 512, 0, stream>>>(xd, nullptr, 256, nullptr, 1,
                                        cls1_wb, 0, ct, nullptr, 128, stats + 7 * 512);
  bnrelu2_k<<<256, 256, 0, stream>>>(ct, stats + 7 * 512, cls1_g, cls1_be, nullptr, nullptr,
                                     ct, nullptr, 128);
  gemm3_k<128><<<512, 512, 0, stream>>>(ct, nullptr, 128, nullptr, 1,
                                        wp6, 0, tb, nullptr, 64, stats + 8 * 512);
  bnrelu2_k<<<128, 256, 0, stream>>>(tb, stats + 8 * 512, cls2_g, cls2_be, nullptr, nullptr,
                                     tb, nullptr, 64);
  cls3_k<<<128, 256, 0, stream>>>(tb, cls3_w, cls3_b, (float*)d_out);
}

// Round 12
// 868.577 us; speedup vs baseline: 1.6027x; 1.0175x over previous
//
#include <hip/hip_runtime.h>

typedef unsigned short u16;
using f16x8 = __attribute__((ext_vector_type(8))) _Float16;  // 8 fp16 (4 VGPRs)
using f32x4 = __attribute__((ext_vector_type(4))) float;

#define V_N 16384
#define M_N 32768

__device__ __forceinline__ float h2f(u16 u) {
  _Float16 h; __builtin_memcpy(&h, &u, 2); return (float)h;
}
__device__ __forceinline__ u16 f2h(float f) {
  _Float16 h = (_Float16)f; u16 u; __builtin_memcpy(&u, &h, 2); return u;
}

// async global->LDS DMA, 16B per lane; LDS dest = wave-uniform base + lane*16
__device__ __forceinline__ void dma16(const u16* g, u16* l) {
  __builtin_amdgcn_global_load_lds(
      (const __attribute__((address_space(1))) void*)(const void*)g,
      (__attribute__((address_space(3))) void*)(void*)l, 16, 0, 0);
}

// ---------- prep (merged into ONE kernel, R12: cut 7 launch gaps) ----------
// Weight permute to FRAGMENT-MAJOR: dst[kc][col][lq][j] (kc = k>>5, lq=(k>>3)&3,
// j=k&7, k = tap*256 + c). One B-load instr = contiguous 1KB (R5/R6 lesson:
// col-strided fragments = 64 scattered lines/instr -> TA serialization).
__device__ __forceinline__ void d_perm2(int bid, const float* __restrict__ w, u16* __restrict__ wp) {
  int o = bid & 255, layer = bid >> 8;
  int t = threadIdx.x;                       // t = input channel c
  const float* src = w + ((size_t)layer * 256 + o) * 3072;
  u16* dst = wp + (size_t)layer * 786432;    // frag-major layer base
  float2 v[6];
  #pragma unroll
  for (int q = 0; q < 6; ++q) v[q] = *(const float2*)(src + t * 12 + q * 2);
  const float* vf = (const float*)v;         // vf[m] = w[o][c=t, tap=m]
  int lo = t & 31;                           // (k&31) = lq*8+j
  #pragma unroll
  for (int m = 0; m < 12; ++m) {
    int kc = m * 8 + (t >> 5);               // k = m*256 + t
    dst[(size_t)kc * 8192 + o * 32 + lo] = f2h(vf[m]);
  }
}

// generic f32 [O][K] row-major -> frag-major fp16 [kc][256][lq][j], zero-pad col>=O
__device__ __forceinline__ void d_permfr(int bid, const float* __restrict__ src, u16* __restrict__ dst,
                                         int O, int K) {
  int i = bid * 256 + threadIdx.x;
  if (i >= (K << 8)) return;
  int j = i & 7, lq = (i >> 3) & 3, col = (i >> 5) & 255, kc = i >> 13;
  int k = kc * 32 + lq * 8 + j;
  float v = (col < O) ? src[(size_t)col * K + k] : 0.f;
  dst[i] = f2h(v);
}

// block ranges: [0,768) perm2 enc | [768,1536) perm2 dec | [1536,3072) permfr skip
// | [3072,3328) permfr cls1 | [3328,3456) permfr cls2 | [3456,3472) zero stats/sesum
__global__ __launch_bounds__(256) void prep_k(
    const float* __restrict__ enc_w, const float* __restrict__ dec_w,
    const float* __restrict__ skip_w, const float* __restrict__ cls1_w,
    const float* __restrict__ cls2_w,
    u16* __restrict__ wpe, u16* __restrict__ wpe_dec, u16* __restrict__ skip_wb,
    u16* __restrict__ cls1_wb, u16* __restrict__ wp6, float* __restrict__ zbase)
{
  int b = blockIdx.x;
  if (b < 768) { d_perm2(b, enc_w, wpe); return; }
  b -= 768;
  if (b < 768) { d_perm2(b, dec_w, wpe_dec); return; }
  b -= 768;
  if (b < 1536) {
    int s = b >> 9, r = b & 511;
    d_permfr(r, skip_w + (size_t)s * 256 * 512, skip_wb + (size_t)s * 256 * 512, 256, 512);
    return;
  }
  b -= 1536;
  if (b < 256) { d_permfr(b, cls1_w, cls1_wb, 128, 256); return; }
  b -= 256;
  if (b < 128) { d_permfr(b, cls2_w, wp6, 64, 128); return; }
  b -= 128;
  // zero stats (10*512 floats) + sesum (4*512 floats) = 7168 floats, contiguous
  int idx = (b * 256 + threadIdx.x) * 2;
  if (idx < 7168) { zbase[idx] = 0.f; zbase[idx + 1] = 0.f; }
}

// per-batch SE-scale fold into frag-major weights
__global__ __launch_bounds__(256) void wscale_k(const u16* __restrict__ w, const float* __restrict__ sig,
                                                const float* __restrict__ sigx,
                                                u16* __restrict__ o, int n, int sel) {
  int i = blockIdx.x * 256 + threadIdx.x;
  if (i >= n) return;
  float wv = h2f(w[i]);
  int k = (i >> 13) * 32 + ((i >> 3) & 3) * 8 + (i & 7);
  int c = k & 255;
  #pragma unroll
  for (int b = 0; b < 2; ++b) {
    float s;
    if (sel == 511 && k < 256) s = sigx ? sigx[b * 256 + c] : 1.f;
    else                       s = sig[b * 256 + c];
    o[(long)b * n + i] = f2h(wv * s);
  }
}

// ---------- encoder block 0 conv (C_in=3, K=36) + FUSED channel stats ----------
__global__ __launch_bounds__(256) void enc0_k(const float* __restrict__ verts, const int* __restrict__ sp,
                                              const float* __restrict__ w0, u16* __restrict__ y,
                                              float* __restrict__ st) {
  __shared__ float xs[32][36];
  int t = threadIdx.x;
  int r0 = blockIdx.x * 32;
  for (int s = t; s < 32 * 12; s += 256) {
    int row = s / 12, tt = s - row * 12;
    int gr = r0 + row;
    int b = gr >> 14, v = gr & (V_N - 1);
    int j = sp[tt * V_N + v];
    const float* p = verts + ((long)b * V_N + j) * 3;
    xs[row][tt]      = p[0];
    xs[row][12 + tt] = p[1];
    xs[row][24 + tt] = p[2];
  }
  __syncthreads();
  float w[36];
  #pragma unroll
  for (int k = 0; k < 36; ++k) w[k] = w0[t * 36 + k];
  float s1 = 0.f, s2 = 0.f;
  for (int row = 0; row < 32; ++row) {
    float a = 0.f;
    #pragma unroll
    for (int k = 0; k < 36; ++k) a += w[k] * xs[row][k];
    u16 h = f2h(a);
    y[(long)(r0 + row) * 256 + t] = h;
    float av = h2f(h);
    s1 += av; s2 += av * av;
  }
  atomicAdd(&st[t], s1);
  atomicAdd(&st[256 + t], s2);
}

// ---------- MFMA GEMM: 64M x 256N, phase-split, frag-major B, interleaved stage ----------
// R9/R11 proven structure (84-88 us/conv): depth-2 counted-vmcnt, 3x8KB buffers,
// ping-pong B register sets (tA/tB2, unroll-2, rule #20), intra-stage pipe
// interleave ({A kp0 + B kp0}|{MFMA}|{idx+dma}|{A kp1 + B kp1}|{MFMA}),
// setprio(1) around MFMA groups (T5).
// Ledger (in-order vmcnt), per-stage issue: lB0,lB1,idx,dma(s+2),lB2,lB3.
//  - ops younger than dma(s+2) = 2 (<=4) -> survives stage-top vmcnt(5).
//  - dma(s) retires during stage s-1's compiler auto-waits (6 younger ops),
//    before the stage-s barrier -> buffer s%3 safe to read.
//  - dma(s+2) writes buf (s-1)%3, whose readers finished before the stage-s
//    barrier that precedes the dma issue -> safe.
// DO-NOT-REVISIT (measured): TPS=2 + JIT B spills (R10, conv 84->142us);
// M=128 1blk/CU convoy (R8, 85->95us); full-tap counted vmcnt (R4, ->147us).
// Current bound is COMPOSITE: LDS-read ~580cy + B-TA ~512 lines + MFMA ~154
// + VALU ~300 per 2190cy block-stage; near-optimal wave decomposition.
template<int CT>
__global__ __launch_bounds__(512, 4) void gemm3_k(
    const u16* __restrict__ P0, const u16* __restrict__ P1, int lda,
    const int* __restrict__ sp, int L,
    const u16* __restrict__ Wt, long wstride,
    u16* __restrict__ Yb, const float* __restrict__ bias, int Ostore,
    float* __restrict__ stats)
{
  constexpr int KC   = CT >> 5;            // k-chunks (32 elems) per tap (8 or 4)
  constexpr int PH   = (CT == 256) ? 4 : 2;// phases -> 64-elem slice always
  constexpr int KCP  = KC / PH;            // k-chunks per stage = 2
  constexpr int PROW = 64;                 // elems per row per stage (128B)
  constexpr int BUFE = 64 * PROW;          // 8KB buffer (u16 elems)
  __shared__ __align__(16) u16 lA[3 * BUFE];   // 3 stage buffers (24KB)
  const int tid  = threadIdx.x;
  const int wave = tid >> 6, lane = tid & 63;
  const int wn = wave * 32;                // N-split-8: 32 cols per wave
  const int lr = lane & 15, lq = lane >> 4;
  // XCD-aware bijective swizzle (nwg % 8 == 0 for all call sites)
  const int nwg = gridDim.x;
  const int wg = (blockIdx.x & 7) * (nwg >> 3) + (blockIdx.x >> 3);
  const int bm = wg * 64;
  const int batch = bm >> 14;
  const int vbase = bm & (V_N - 1);
  const int qrow = lane >> 3;              // row within DMA instr (8 rows/instr)
  const int qchunk = lane & 7;             // 16B chunk within 128B slice
  const bool gat = (sp != nullptr);
  const long rowb = (long)batch * V_N;     // gather row base (rows)
  const u16* Pd1 = P1 ? P1 : P0;
  const u16* Wb = Wt + (long)batch * wstride;
  const int NS = PH * L;                   // total stages (even)

  // frag-major B pointers: fragment (col=wn+nt*16+lr, half lq) of kchunk kc at
  // Wb + kc*8192 + col*32 + lq*8  (64 lanes of one instr -> contiguous 1KB)
  const u16* bp[2];
  #pragma unroll
  for (int nt = 0; nt < 2; ++nt)
    bp[nt] = Wb + ((long)(wn + nt * 16 + lr) * 4 + lq) * 8;

  // lane-constant A-read addresses (elems from lA base); per-stage cost = +bufoff
  const u16* aBase[4][2];
  #pragma unroll
  for (int mt = 0; mt < 4; ++mt)
    #pragma unroll
    for (int kp = 0; kp < 2; ++kp) {
      int row = mt * 16 + lr;
      aBase[mt][kp] = lA + row * PROW + (((kp * 4 + lq) ^ (row & 7)) << 3);
    }

  auto load_idx = [&](int tap) -> int {
    int v = 0;
    if (gat && lane < 8) v = sp[(long)tap * V_N + vbase + wave * 8 + lane];
    return v;
  };

  // stage DMA: 64 rows x 128B slice; wave w covers rows [w*8, w*8+8), 1 instr
  auto dma_st = [&](u16* buf, const u16* src, int idxreg, int ph) {
    u16* wb = buf + wave * (8 * PROW);
    int rloc = wave * 8 + qrow;
    long grow;
    if (gat) grow = rowb + (long)__shfl(idxreg, qrow, 64);
    else     grow = bm + rloc;
    const u16* gp = src + grow * lda + ph * PROW + ((qchunk ^ (rloc & 7)) << 3);
    dma16(gp, wb);
  };

  f32x4 acc[4][2];
  #pragma unroll
  for (int i = 0; i < 4; ++i)
    #pragma unroll
    for (int j = 0; j < 2; ++j) acc[i][j] = (f32x4){0.f, 0.f, 0.f, 0.f};

  f16x8 tA[KCP * 2], tB2[KCP * 2];

  // rolling stage descriptors: (lB,phB)=stage s+1, (lD,phD)=stage s+2, lI=tap(s+3)
  auto adv = [&](int& l, int& ph) { if (++l == L) { l = 0; ++ph; } };
  int lB = 0, phB = 0; adv(lB, phB);
  int lD = lB, phD = phB; adv(lD, phD);
  int lI = lD; { int pT = phD; int lT = lI; adv(lT, pT); lI = lT; }
  int idxN;   // idx for the dma issued at the CURRENT stage (stage s -> dma(s+2))

  // ---- prologue: idx(tap0,tap1,tap2); dma(0); dma(1); loadB(0) ----
  {
    int i0 = load_idx(0);
    int i1 = load_idx(lB);
    idxN = load_idx(lD);
    dma_st(lA, P0, i0, 0);
    if (NS > 1) {
      const u16* s1 = (!gat && lB > 0) ? Pd1 : P0;
      dma_st(lA + BUFE, s1, i1, phB);
    }
    __builtin_amdgcn_sched_barrier(0);
    #pragma unroll
    for (int kp = 0; kp < KCP; ++kp)
      #pragma unroll
      for (int nt = 0; nt < 2; ++nt)
        tA[kp * 2 + nt] = *(const f16x8*)(bp[nt] + (long)kp * 8192);
    __builtin_amdgcn_sched_barrier(0);
  }

  auto stage = [&](int s, f16x8 (&tCur)[KCP * 2], f16x8 (&tNxt)[KCP * 2]) {
    if (s + 1 < NS) asm volatile("s_waitcnt vmcnt(5)" ::: "memory");
    else            asm volatile("s_waitcnt vmcnt(0)" ::: "memory");
    asm volatile("s_waitcnt lgkmcnt(0)" ::: "memory");
    __builtin_amdgcn_s_barrier();
    __builtin_amdgcn_sched_barrier(0);
    const int so = (s % 3) * BUFE;
    const long cbB = (long)(lB * KC + phB * KCP);
    // group 1: A kp0 reads + B(s+1) kp0 half
    f16x8 a0[4];
    #pragma unroll
    for (int mt = 0; mt < 4; ++mt) a0[mt] = *(const f16x8*)(aBase[mt][0] + so);
    if (s + 1 < NS) {
      tNxt[0] = *(const f16x8*)(bp[0] + cbB * 8192);
      tNxt[1] = *(const f16x8*)(bp[1] + cbB * 8192);
    }
    __builtin_amdgcn_sched_barrier(0);
    // group 2: MFMA kp0
    __builtin_amdgcn_s_setprio(1);
    #pragma unroll
    for (int mt = 0; mt < 4; ++mt) {
      acc[mt][0] = __builtin_amdgcn_mfma_f32_16x16x32_f16(a0[mt], tCur[0], acc[mt][0], 0, 0, 0);
      acc[mt][1] = __builtin_amdgcn_mfma_f32_16x16x32_f16(a0[mt], tCur[1], acc[mt][1], 0, 0, 0);
    }
    __builtin_amdgcn_s_setprio(0);
    __builtin_amdgcn_sched_barrier(0);
    // group 3: idx + dma(s+2)
    int idxT = 0;
    if (gat && s + 3 < NS) idxT = load_idx(lI);
    if (s + 2 < NS) {
      const u16* srcD = (!gat && lD > 0) ? Pd1 : P0;
      dma_st(lA + ((s + 2) % 3) * BUFE, srcD, idxN, phD);
    }
    __builtin_amdgcn_sched_barrier(0);
    // group 4: A kp1 reads + B(s+1) kp1 half
    f16x8 a1[4];
    #pragma unroll
    for (int mt = 0; mt < 4; ++mt) a1[mt] = *(const f16x8*)(aBase[mt][1] + so);
    if (s + 1 < NS) {
      tNxt[2] = *(const f16x8*)(bp[0] + (cbB + 1) * 8192);
      tNxt[3] = *(const f16x8*)(bp[1] + (cbB + 1) * 8192);
    }
    __builtin_amdgcn_sched_barrier(0);
    // group 5: MFMA kp1
    __builtin_amdgcn_s_setprio(1);
    #pragma unroll
    for (int mt = 0; mt < 4; ++mt) {
      acc[mt][0] = __builtin_amdgcn_mfma_f32_16x16x32_f16(a1[mt], tCur[2], acc[mt][0], 0, 0, 0);
      acc[mt][1] = __builtin_amdgcn_mfma_f32_16x16x32_f16(a1[mt], tCur[3], acc[mt][1], 0, 0, 0);
    }
    __builtin_amdgcn_s_setprio(0);
    adv(lB, phB); adv(lD, phD); if (++lI == L) lI = 0;
    idxN = idxT;
  };

  for (int s = 0; s < NS; s += 2) {
    stage(s, tA, tB2);
    stage(s + 1, tB2, tA);
  }

  // epilogue: C/D layout col=lane&15, row=(lane>>4)*4+reg [guide m89]; fused stats
  #pragma unroll
  for (int nt = 0; nt < 2; ++nt) {
    int col = wn + nt * 16 + lr;
    if (col < Ostore) {
      float bv = bias ? bias[col] : 0.f;
      float s1 = 0.f, s2 = 0.f;
      #pragma unroll
      for (int mt = 0; mt < 4; ++mt) {
        #pragma unroll
        for (int rg = 0; rg < 4; ++rg) {
          int row = bm + mt * 16 + lq * 4 + rg;
          float v = acc[mt][nt][rg] + bv;
          Yb[(long)row * Ostore + col] = f2h(v);
          s1 += v; s2 += v * v;
        }
      }
      if (stats) {
        s1 += __shfl_xor(s1, 16); s1 += __shfl_xor(s1, 32);
        s2 += __shfl_xor(s2, 16); s2 += __shfl_xor(s2, 32);
        if (lq == 0) {
          atomicAdd(&stats[col], s1);
          atomicAdd(&stats[Ostore + col], s2);
        }
      }
    }
  }
}

// ---------- vectorized BN+ReLU (+fp16 residual, optional per-channel resid scale) (+SE sums) ----------
__global__ __launch_bounds__(256) void bnrelu2_k(
    const u16* __restrict__ y, const float* __restrict__ st,
    const float* __restrict__ g, const float* __restrict__ be,
    const u16* __restrict__ resid, const float* __restrict__ rscale,
    u16* __restrict__ ob, float* __restrict__ ses, int O)
{
  __shared__ float sL[256];
  int tid = threadIdx.x;
  int tpr = O >> 2;
  int rpi = 256 / tpr;
  int ci = (tid & (tpr - 1)) * 4;
  int row0 = blockIdx.x * (rpi * 16);
  int r0 = row0 + (tid / tpr);
  int b = row0 >> 14;
  float mean[4], sc[4], sh[4], rs[4];
  #pragma unroll
  for (int j = 0; j < 4; ++j) {
    int c = ci + j;
    float m = st[c] * (1.f / 32768.f);
    float var = st[O + c] * (1.f / 32768.f) - m * m;
    mean[j] = m;
    sc[j] = rsqrtf(fmaxf(var, 0.f) + 1e-5f) * g[c];
    sh[j] = be[c];
    rs[j] = rscale ? rscale[b * 256 + c] : 1.f;
  }
  float ss[4] = {0,0,0,0};
  for (int it = 0; it < 16; ++it) {
    long i = ((long)r0 + (long)it * rpi) * O + ci;
    uint2 pv = *(const uint2*)(y + i);
    float v[4];
    v[0] = fmaxf((h2f((u16)(pv.x & 0xffff)) - mean[0]) * sc[0] + sh[0], 0.f);
    v[1] = fmaxf((h2f((u16)(pv.x >> 16))    - mean[1]) * sc[1] + sh[1], 0.f);
    v[2] = fmaxf((h2f((u16)(pv.y & 0xffff)) - mean[2]) * sc[2] + sh[2], 0.f);
    v[3] = fmaxf((h2f((u16)(pv.y >> 16))    - mean[3]) * sc[3] + sh[3], 0.f);
    if (resid) {
      uint2 rv = *(const uint2*)(resid + i);
      v[0] += h2f((u16)(rv.x & 0xffff)) * rs[0]; v[1] += h2f((u16)(rv.x >> 16)) * rs[1];
      v[2] += h2f((u16)(rv.y & 0xffff)) * rs[2]; v[3] += h2f((u16)(rv.y >> 16)) * rs[3];
    }
    uint2 pk;
    pk.x = (unsigned)f2h(v[0]) | ((unsigned)f2h(v[1]) << 16);
    pk.y = (unsigned)f2h(v[2]) | ((unsigned)f2h(v[3]) << 16);
    *(uint2*)(ob + i) = pk;
    #pragma unroll
    for (int j = 0; j < 4; ++j) ss[j] += v[j];
  }
  if (ses) {
    sL[tid] = 0.f;
    __syncthreads();
    #pragma unroll
    for (int j = 0; j < 4; ++j) atomicAdd(&sL[ci + j], ss[j]);
    __syncthreads();
    atomicAdd(&ses[b * O + tid], sL[tid]);
  }
}

// ---------- SE gate ----------
__global__ void se_k(const float* __restrict__ ses, const float* __restrict__ w1,
                     const float* __restrict__ w2, float* __restrict__ sig)
{
  __shared__ float s[256];
  __shared__ float h[32];
  int b = blockIdx.x, t = threadIdx.x;
  s[t] = ses[b * 256 + t] * (1.f / 16384.f);
  __syncthreads();
  if (t < 32) {
    float a = 0.f;
    for (int c = 0; c < 256; ++c) a += w1[t * 256 + c] * s[c];
    h[t] = fmaxf(a, 0.f);
  }
  __syncthreads();
  float a = 0.f;
  #pragma unroll
  for (int r = 0; r < 32; ++r) a += w2[t * 32 + r] * h[r];
  sig[b * 256 + t] = 1.f / (1.f + expf(-a));
}

// ---------- final head ----------
__global__ __launch_bounds__(256) void cls3_k(const u16* __restrict__ h2, const float* __restrict__ w,
                                              const float* __restrict__ b, float* __restrict__ out)
{
  __shared__ float ws[64];
  int t = threadIdx.x;
  if (t < 64) ws[t] = w[t];
  __syncthreads();
  int r = blockIdx.x * 256 + t;
  const u16* p = h2 + (long)r * 64;
  float a = b[0];
  #pragma unroll
  for (int c = 0; c < 64; ++c) a += ws[c] * h2f(p[c]);
  out[r] = a;
}

extern "C" void kernel_launch(void* const* d_in, const int* in_sizes, int n_in,
                              void* d_out, int out_size, void* d_ws, size_t ws_size,
                              hipStream_t stream)
{
  (void)in_sizes; (void)n_in; (void)out_size; (void)ws_size;
  const float* verts   = (const float*)d_in[0];
  const int*   spirals = (const int*)d_in[1];
  const float* enc0_w  = (const float*)d_in[2];
  const float* enc0_g  = (const float*)d_in[4];
  const float* enc0_be = (const float*)d_in[5];
  const float* enc_w   = (const float*)d_in[6];
  const float* enc_g   = (const float*)d_in[8];
  const float* enc_be  = (const float*)d_in[9];
  const float* se_w1   = (const float*)d_in[10];
  const float* se_w2   = (const float*)d_in[11];
  const float* skip_w  = (const float*)d_in[12];
  const float* skip_b  = (const float*)d_in[13];
  const float* dec_w   = (const float*)d_in[14];
  const float* dec_g   = (const float*)d_in[16];
  const float* dec_be  = (const float*)d_in[17];
  const float* cls1_w  = (const float*)d_in[18];
  const float* cls1_g  = (const float*)d_in[20];
  const float* cls1_be = (const float*)d_in[21];
  const float* cls2_w  = (const float*)d_in[22];
  const float* cls2_g  = (const float*)d_in[24];
  const float* cls2_be = (const float*)d_in[25];
  const float* cls3_w  = (const float*)d_in[26];
  const float* cls3_b  = (const float*)d_in[27];

  // --- workspace (~118 MB) ---
  char* p = (char*)d_ws;
  auto alloc = [&](size_t n) { char* q = p; p += (n + 255) & ~(size_t)255; return q; };
  u16* wpe     = (u16*)alloc((size_t)6 * 256 * 3072 * 2);       // 6 permuted conv weights
  u16* wpe_s   = (u16*)alloc((size_t)3 * 2 * 256 * 3072 * 2);   // enc, per-batch SE-folded
  u16* skip_wb = (u16*)alloc((size_t)3 * 256 * 512 * 2);
  u16* skip_s  = (u16*)alloc((size_t)3 * 2 * 256 * 512 * 2);    // skip, per-batch folded
  u16* cls1_wb = (u16*)alloc((size_t)256 * 256 * 2);            // zero-padded to 256 cols
  u16* wp6     = (u16*)alloc((size_t)256 * 128 * 2);            // zero-padded to 256 cols
  // zeroed region: 10 stats slots + 4 sesum slots (zeroed inside prep_k)
  float* stats = (float*)alloc(10 * 2048);                      // slot i = stats + i*512
  float* sesum = (float*)alloc(4 * 2048);                       // slot i = sesum + i*512
  float* sig   = (float*)alloc(4 * 2048);                       // sig_i = sig + i*512
  u16* out0 = (u16*)alloc((size_t)M_N * 256 * 2);
  u16* out1 = (u16*)alloc((size_t)M_N * 256 * 2);
  u16* out2 = (u16*)alloc((size_t)M_N * 256 * 2);
  u16* ct   = (u16*)alloc((size_t)M_N * 256 * 2);               // conv temp; aliases out3
  u16* tb   = (u16*)alloc((size_t)M_N * 256 * 2);
  u16* xd   = (u16*)alloc((size_t)M_N * 256 * 2);
  u16* outs[4] = {out0, out1, out2, ct};
  const size_t WENC = (size_t)256 * 3072;      // elems per enc weight copy
  const size_t WSKP = (size_t)256 * 512;

  // ---- single merged prep dispatch (perms + zeroing; was 8 dispatches) ----
  prep_k<<<3472, 256, 0, stream>>>(enc_w, dec_w, skip_w, cls1_w, cls2_w,
                                   wpe, wpe + (size_t)3 * WENC, skip_wb, cls1_wb, wp6,
                                   stats);

  // ---- encoder block 0 (stats fused into enc0) ----
  enc0_k<<<1024, 256, 0, stream>>>(verts, spirals, enc0_w, ct, stats);
  bnrelu2_k<<<512, 256, 0, stream>>>(ct, stats, enc0_g, enc0_be, nullptr, nullptr, out0, sesum, 256);
  se_k<<<2, 256, 0, stream>>>(sesum, se_w1, se_w2, sig);

  // ---- encoder blocks 1..3 (SE scale folded into per-batch weights) ----
  for (int i = 1; i < 4; ++i) {
    wscale_k<<<3072, 256, 0, stream>>>(wpe + (size_t)(i - 1) * WENC, sig + (i - 1) * 512, nullptr,
                                       wpe_s + (size_t)(i - 1) * 2 * WENC, (int)WENC, 255);
    gemm3_k<256><<<512, 512, 0, stream>>>(outs[i - 1], nullptr, 256,
                                          spirals + (size_t)i * V_N * 12, 12,
                                          wpe_s + (size_t)(i - 1) * 2 * WENC, (long)WENC,
                                          ct, nullptr, 256, stats + i * 512);
    bnrelu2_k<<<512, 256, 0, stream>>>(ct, stats + i * 512, enc_g + (i - 1) * 256, enc_be + (i - 1) * 256,
                                       outs[i - 1], sig + (i - 1) * 512, outs[i], sesum + i * 512, 256);
    se_k<<<2, 256, 0, stream>>>(sesum + i * 512, se_w1 + (size_t)i * 32 * 256,
                                se_w2 + (size_t)i * 256 * 32, sig + i * 512);
  }

  // ---- decoder blocks (decoder input SE-scale folded into skip weights at i=0) ----
  for (int i = 0; i < 3; ++i) {
    wscale_k<<<512, 256, 0, stream>>>(skip_wb + (size_t)i * WSKP, sig + (2 - i) * 512,
                                      (i == 0) ? (sig + 3 * 512) : nullptr,
                                      skip_s + (size_t)i * 2 * WSKP, (int)WSKP, 511);
    gemm3_k<256><<<512, 512, 0, stream>>>((i == 0) ? ct : xd, outs[2 - i], 256, nullptr, 2,
                                          skip_s + (size_t)i * 2 * WSKP, (long)WSKP,
                                          tb, skip_b + i * 256, 256, nullptr);       // x1 -> tb
    gemm3_k<256><<<512, 512, 0, stream>>>(tb, nullptr, 256,
                                          spirals + (size_t)(2 - i) * V_N * 12, 12,
                                          wpe + (size_t)(3 + i) * WENC, 0,
                                          outs[2 - i], nullptr, 256, stats + (4 + i) * 512);
    bnrelu2_k<<<512, 256, 0, stream>>>(outs[2 - i], stats + (4 + i) * 512, dec_g + i * 256, dec_be + i * 256,
                                       tb, nullptr, xd, nullptr, 256);                // x -> xd
  }

  // ---- classifier ----
  gemm3_k<256><<<512, 512, 0, stream>>>(xd, nullptr, 256, nullptr, 1,
                                        cls1_wb, 0, ct, nullptr, 128, stats + 7 * 512);
  bnrelu2_k<<<256, 256, 0, stream>>>(ct, stats + 7 * 512, cls1_g, cls1_be, nullptr, nullptr,
                                     ct, nullptr, 128);
  gemm3_k<128><<<512, 512, 0, stream>>>(ct, nullptr, 128, nullptr, 1,
                                        wp6, 0, tb, nullptr, 64, stats + 8 * 512);
  bnrelu2_k<<<128, 256, 0, stream>>>(tb, stats + 8 * 512, cls2_g, cls2_be, nullptr, nullptr,
                                     tb, nullptr, 64);
  cls3_k<<<128, 256, 0, stream>>>(tb, cls3_w, cls3_b, (float*)d_out);
}